// Round 1
// baseline (1283.177 us; speedup 1.0000x reference)
//
#include <hip/hip_runtime.h>

#define B_   4
#define S_   256
#define E_   256
#define H_   8
#define DH_  32
#define LD_  128
#define N_   65536
#define NC_  2
#define PK   68   // padded row stride for 64-wide k tiles (16B aligned, conflict-light)

// ---------------------------------------------------------------------------
// K0: cluster_ids = repeat(arange(S), np_cluster, total_repeat_length=N)
// ---------------------------------------------------------------------------
__global__ __launch_bounds__(256) void build_ids_k(const int* __restrict__ npc,
                                                   int* __restrict__ ids) {
  __shared__ int pre[S_ + 1];
  int t = threadIdx.x;
  if (t == 0) {
    pre[0] = 0;
    for (int s = 0; s < S_; s++) pre[s + 1] = pre[s] + npc[s];
  }
  __syncthreads();
  for (int n = t; n < N_; n += 256) ids[n] = S_ - 1;  // pad-with-last semantics
  __syncthreads();
  int s = t;  // 256 threads == S_
  int st = pre[s];
  int en = pre[s + 1]; if (en > N_) en = N_;
  for (int n = st; n < en; n++) ids[n] = s;
}

// ---------------------------------------------------------------------------
// K1: pos-MLP + add gl_feats^T  ->  x[b][s][e]
// ---------------------------------------------------------------------------
__global__ __launch_bounds__(256) void pos_x_k(const float* __restrict__ gl,
                                               const float* __restrict__ cen,
                                               const float* __restrict__ fc1w,
                                               const float* __restrict__ fc1b,
                                               const float* __restrict__ fc2w,
                                               const float* __restrict__ fc2b,
                                               float* __restrict__ x) {
  int bs = blockIdx.x;          // b*S + s
  int b = bs >> 8, s = bs & 255;
  __shared__ float hsh[16];
  int t = threadIdx.x;
  if (t < 16) {
    float c0 = cen[bs * 2 + 0], c1 = cen[bs * 2 + 1];
    float v = c0 * fc1w[2 * t] + c1 * fc1w[2 * t + 1] + fc1b[t];
    hsh[t] = (v >= 0.f) ? v : 0.01f * v;   // leaky relu
  }
  __syncthreads();
  float p = fc2b[t];
#pragma unroll
  for (int j = 0; j < 16; j++) p += hsh[j] * fc2w[t * 16 + j];
  x[(size_t)bs * E_ + t] = gl[((size_t)s * B_ + b) * E_ + t] + p;
}

// ---------------------------------------------------------------------------
// K2/K4: generic fp32 GEMM  C[M][N] = A[M][K] @ W[N][K]^T + bias
// 64x64 tile, BK=64, 4x4 micro-tile per thread, 256 threads
// ---------------------------------------------------------------------------
__global__ __launch_bounds__(256) void gemm64_k(const float* __restrict__ A,
                                                const float* __restrict__ W,
                                                const float* __restrict__ bias,
                                                float* __restrict__ C,
                                                int M, int N, int K) {
  __shared__ __align__(16) float sA[64 * PK];
  __shared__ __align__(16) float sW[64 * PK];
  int t = threadIdx.x;
  int row0 = blockIdx.x * 64, col0 = blockIdx.y * 64;
  int tp = t & 15, tc = t >> 4;
  int srow = t >> 4, sk4 = (t & 15) * 4;
  float acc[4][4];
#pragma unroll
  for (int i = 0; i < 4; i++)
#pragma unroll
    for (int j = 0; j < 4; j++) acc[i][j] = 0.f;

  for (int kc = 0; kc < K; kc += 64) {
    __syncthreads();
#pragma unroll
    for (int i = 0; i < 4; i++) {
      int r = i * 16 + srow;
      *(float4*)&sA[r * PK + sk4] = *(const float4*)&A[(size_t)(row0 + r) * K + kc + sk4];
      *(float4*)&sW[r * PK + sk4] = *(const float4*)&W[(size_t)(col0 + r) * K + kc + sk4];
    }
    __syncthreads();
#pragma unroll
    for (int k4 = 0; k4 < 64; k4 += 4) {
      float4 a[4], w[4];
#pragma unroll
      for (int i = 0; i < 4; i++) a[i] = *(const float4*)&sA[(4 * tp + i) * PK + k4];
#pragma unroll
      for (int i = 0; i < 4; i++) w[i] = *(const float4*)&sW[(4 * tc + i) * PK + k4];
#pragma unroll
      for (int pi = 0; pi < 4; pi++)
#pragma unroll
        for (int ci = 0; ci < 4; ci++)
          acc[pi][ci] += a[pi].x * w[ci].x + a[pi].y * w[ci].y +
                         a[pi].z * w[ci].z + a[pi].w * w[ci].w;
    }
  }
#pragma unroll
  for (int pi = 0; pi < 4; pi++) {
    int r = row0 + 4 * tp + pi;
    int c = col0 + 4 * tc;
    float4 o;
    o.x = acc[pi][0] + bias[c + 0];
    o.y = acc[pi][1] + bias[c + 1];
    o.z = acc[pi][2] + bias[c + 2];
    o.w = acc[pi][3] + bias[c + 3];
    *(float4*)&C[(size_t)r * N + c] = o;
  }
}

// ---------------------------------------------------------------------------
// K3: attention. grid = B*H*4 blocks; block = (b, h, 64 q-rows).
// 256 threads = 4 waves; wave g handles k-range [g*64, g*64+64) for all 64 rows
// (per-wave uniform k index -> LDS broadcast reads). Split-K softmax merge in LDS.
// ---------------------------------------------------------------------------
__global__ __launch_bounds__(256) void attn_k(const float* __restrict__ qkv,
                                              float* __restrict__ ctxo) {
  int bid = blockIdx.x;
  int qt = bid & 3, h = (bid >> 2) & 7, b = bid >> 5;
  __shared__ __align__(16) float smem[16384];  // 64 KB
  float* Kx = smem;          // [256][32]
  float* Vx = smem + 8192;   // [256][32]
  int t = threadIdx.x;
#pragma unroll
  for (int i = 0; i < 8; i++) {
    int row = i * 32 + (t >> 3);
    int d4 = (t & 7) * 4;
    const float* base = qkv + (size_t)(b * S_ + row) * 768 + h * 32 + d4;
    *(float4*)&Kx[row * 32 + d4] = *(const float4*)(base + 256);
    *(float4*)&Vx[row * 32 + d4] = *(const float4*)(base + 512);
  }
  int r = t & 63, g = t >> 6;
  float q[32];
  {
    const float* qb = qkv + (size_t)(b * S_ + qt * 64 + r) * 768 + h * 32;
#pragma unroll
    for (int d4 = 0; d4 < 32; d4 += 4) {
      float4 v = *(const float4*)(qb + d4);
      q[d4] = v.x; q[d4 + 1] = v.y; q[d4 + 2] = v.z; q[d4 + 3] = v.w;
    }
  }
  __syncthreads();
  const float scale = 0.17677669529663687f;  // 1/sqrt(32)
  int kk0 = g * 64;
  // pass 1: group max
  float m = -1e30f;
  for (int kk = kk0; kk < kk0 + 64; kk++) {
    const float* kr = &Kx[kk * 32];
    float s = 0.f;
#pragma unroll
    for (int d4 = 0; d4 < 32; d4 += 4) {
      float4 kv = *(const float4*)(kr + d4);
      s += q[d4] * kv.x + q[d4 + 1] * kv.y + q[d4 + 2] * kv.z + q[d4 + 3] * kv.w;
    }
    m = fmaxf(m, s * scale);
  }
  // pass 2: exp-sum + ctx accumulate
  float l = 0.f;
  float ctx[32];
#pragma unroll
  for (int d = 0; d < 32; d++) ctx[d] = 0.f;
  for (int kk = kk0; kk < kk0 + 64; kk++) {
    const float* kr = &Kx[kk * 32];
    const float* vr = &Vx[kk * 32];
    float s = 0.f;
#pragma unroll
    for (int d4 = 0; d4 < 32; d4 += 4) {
      float4 kv = *(const float4*)(kr + d4);
      s += q[d4] * kv.x + q[d4 + 1] * kv.y + q[d4 + 2] * kv.z + q[d4 + 3] * kv.w;
    }
    float p = __expf(s * scale - m);
    l += p;
#pragma unroll
    for (int d4 = 0; d4 < 32; d4 += 4) {
      float4 vv = *(const float4*)(vr + d4);
      ctx[d4] += p * vv.x; ctx[d4 + 1] += p * vv.y;
      ctx[d4 + 2] += p * vv.z; ctx[d4 + 3] += p * vv.w;
    }
  }
  __syncthreads();  // K/V dead; overlay merge buffers
  float* ctxbuf = smem;              // [4][64][32] with per-row rotation
  float* mbuf = smem + 8192;         // [4][64]
  float* lbuf = smem + 8192 + 256;   // [4][64]
  mbuf[g * 64 + r] = m;
  lbuf[g * 64 + r] = l;
#pragma unroll
  for (int d = 0; d < 32; d++)
    ctxbuf[(g * 64 + r) * 32 + ((d + r) & 31)] = ctx[d];  // rotate: bank-conflict-free
  __syncthreads();
  int r2 = t & 63, dq = t >> 6;
  float M = fmaxf(fmaxf(mbuf[r2], mbuf[64 + r2]), fmaxf(mbuf[128 + r2], mbuf[192 + r2]));
  float wg[4]; float L = 0.f;
#pragma unroll
  for (int gg = 0; gg < 4; gg++) {
    wg[gg] = __expf(mbuf[gg * 64 + r2] - M);
    L += lbuf[gg * 64 + r2] * wg[gg];
  }
  float invL = 1.f / L;
  float* orow = ctxo + (size_t)(b * S_ + qt * 64 + r2) * E_ + h * 32;
#pragma unroll
  for (int dd = 0; dd < 8; dd++) {
    int d = dq * 8 + dd;
    float o = 0.f;
#pragma unroll
    for (int gg = 0; gg < 4; gg++)
      o += ctxbuf[(gg * 64 + r2) * 32 + ((d + r2) & 31)] * wg[gg];
    orow[d] = o * invL;
  }
}

// ---------------------------------------------------------------------------
// K5: fused conv2+bn2+relu -> conv3+bn3+relu -> conv4, per 64-point tile.
// pc row = [lo_feats(128) | attn_out[ids[n]](256)], K=384 in 6 chunks of 64.
// h2/h3 never leave LDS. 52 KB LDS -> 3 blocks/CU.
// ---------------------------------------------------------------------------
__global__ __launch_bounds__(256) void conv_fused_k(
    const float* __restrict__ lo, const float* __restrict__ attn,
    const int* __restrict__ ids,
    const float* __restrict__ w2, const float* __restrict__ b2,
    const float* __restrict__ g2, const float* __restrict__ be2,
    const float* __restrict__ mu2, const float* __restrict__ va2,
    const float* __restrict__ w3, const float* __restrict__ b3,
    const float* __restrict__ g3, const float* __restrict__ be3,
    const float* __restrict__ mu3, const float* __restrict__ va3,
    const float* __restrict__ w4, const float* __restrict__ b4,
    float* __restrict__ out) {
  __shared__ __align__(16) float R0[64 * PK];
  __shared__ __align__(16) float R1[64 * PK];
  __shared__ __align__(16) float R2[64 * PK];
  int t = threadIdx.x;
  int bid = blockIdx.x;
  int b = bid >> 10;
  int n0 = (bid & 1023) << 6;
  int tp = t & 15, tc = t >> 4;
  int srow = t >> 4, sk4 = (t & 15) * 4;

  float acc2[2][4][4];
#pragma unroll
  for (int hh = 0; hh < 2; hh++)
#pragma unroll
    for (int i = 0; i < 4; i++)
#pragma unroll
      for (int j = 0; j < 4; j++) acc2[hh][i][j] = 0.f;

  // ---- conv2: K = 384 (6 chunks of 64), 128 out channels (2 halves of 64)
  for (int kc = 0; kc < 6; kc++) {
    __syncthreads();  // previous micro-loop reads of R0 done
#pragma unroll
    for (int i = 0; i < 4; i++) {
      int rr = i * 16 + srow;
      int n = n0 + rr;
      float4 v;
      if (kc < 2) {
        v = *(const float4*)&lo[((size_t)b * N_ + n) * LD_ + kc * 64 + sk4];
      } else {
        int s = ids[n];
        v = *(const float4*)&attn[((size_t)b * S_ + s) * E_ + (kc - 2) * 64 + sk4];
      }
      *(float4*)&R0[rr * PK + sk4] = v;
    }
    for (int hh = 0; hh < 2; hh++) {
      __syncthreads();  // previous micro reads of R1 done
#pragma unroll
      for (int i = 0; i < 4; i++) {
        int ch = i * 16 + srow;
        *(float4*)&R1[ch * PK + sk4] =
            *(const float4*)&w2[(size_t)(hh * 64 + ch) * 384 + kc * 64 + sk4];
      }
      __syncthreads();  // R0+R1 visible
#pragma unroll
      for (int k4 = 0; k4 < 64; k4 += 4) {
        float4 a[4], w[4];
#pragma unroll
        for (int i = 0; i < 4; i++) a[i] = *(const float4*)&R0[(4 * tp + i) * PK + k4];
#pragma unroll
        for (int i = 0; i < 4; i++) w[i] = *(const float4*)&R1[(4 * tc + i) * PK + k4];
#pragma unroll
        for (int pi = 0; pi < 4; pi++)
#pragma unroll
          for (int ci = 0; ci < 4; ci++)
            acc2[hh][pi][ci] += a[pi].x * w[ci].x + a[pi].y * w[ci].y +
                                a[pi].z * w[ci].z + a[pi].w * w[ci].w;
      }
    }
  }
  __syncthreads();  // all conv2 reads done; R0/R1 reusable

  // ---- bn2 + relu -> h2 in LDS: R0 = ch 0..63, R1 = ch 64..127 ([point][ch])
#pragma unroll
  for (int hh = 0; hh < 2; hh++) {
    float* dst = hh ? R1 : R0;
#pragma unroll
    for (int ci = 0; ci < 4; ci++) {
      int ch = hh * 64 + 4 * tc + ci;
      float sc = g2[ch] * rsqrtf(va2[ch] + 1e-5f);
      float sh = be2[ch] - mu2[ch] * sc;
      float bb = b2[ch];
#pragma unroll
      for (int pi = 0; pi < 4; pi++) {
        float z = (acc2[hh][pi][ci] + bb) * sc + sh;
        dst[(4 * tp + pi) * PK + 4 * tc + ci] = fmaxf(z, 0.f);
      }
    }
  }

  // ---- conv3: K = 128 (chunk 0 = R0, chunk 1 = R1), 64 out channels
  float acc3[4][4];
#pragma unroll
  for (int i = 0; i < 4; i++)
#pragma unroll
    for (int j = 0; j < 4; j++) acc3[i][j] = 0.f;
  for (int kc3 = 0; kc3 < 2; kc3++) {
    __syncthreads();  // h2 writes visible / prev reads of R2 done
#pragma unroll
    for (int i = 0; i < 4; i++) {
      int ch = i * 16 + srow;
      *(float4*)&R2[ch * PK + sk4] =
          *(const float4*)&w3[(size_t)ch * 128 + kc3 * 64 + sk4];
    }
    __syncthreads();
    const float* Ar = kc3 ? R1 : R0;
#pragma unroll
    for (int k4 = 0; k4 < 64; k4 += 4) {
      float4 a[4], w[4];
#pragma unroll
      for (int i = 0; i < 4; i++) a[i] = *(const float4*)&Ar[(4 * tp + i) * PK + k4];
#pragma unroll
      for (int i = 0; i < 4; i++) w[i] = *(const float4*)&R2[(4 * tc + i) * PK + k4];
#pragma unroll
      for (int pi = 0; pi < 4; pi++)
#pragma unroll
        for (int ci = 0; ci < 4; ci++)
          acc3[pi][ci] += a[pi].x * w[ci].x + a[pi].y * w[ci].y +
                          a[pi].z * w[ci].z + a[pi].w * w[ci].w;
    }
  }
  __syncthreads();  // conv3 reads done

  // ---- bn3 + relu -> h3 into R2 ([point][ch])
#pragma unroll
  for (int ci = 0; ci < 4; ci++) {
    int ch = 4 * tc + ci;
    float sc = g3[ch] * rsqrtf(va3[ch] + 1e-5f);
    float sh = be3[ch] - mu3[ch] * sc;
    float bb = b3[ch];
#pragma unroll
    for (int pi = 0; pi < 4; pi++) {
      float z = (acc3[pi][ci] + bb) * sc + sh;
      R2[(4 * tp + pi) * PK + ch] = fmaxf(z, 0.f);
    }
  }
  __syncthreads();

  // ---- conv4: out[b][c][n] (c = 0..1), K = 64
  if (t < 128) {
    int c = t >> 6, p = t & 63;
    float s = b4[c];
#pragma unroll
    for (int k = 0; k < 64; k++) s += R2[p * PK + k] * w4[c * 64 + k];
    out[((size_t)b * NC_ + c) * N_ + n0 + p] = s;
  }
}

// ---------------------------------------------------------------------------
extern "C" void kernel_launch(void* const* d_in, const int* in_sizes, int n_in,
                              void* d_out, int out_size, void* d_ws, size_t ws_size,
                              hipStream_t stream) {
  const float* gl   = (const float*)d_in[0];
  const float* lo   = (const float*)d_in[1];
  const float* cen  = (const float*)d_in[2];
  const int*   npc  = (const int*)d_in[3];
  const float* fc1w = (const float*)d_in[4];
  const float* fc1b = (const float*)d_in[5];
  const float* fc2w = (const float*)d_in[6];
  const float* fc2b = (const float*)d_in[7];
  const float* ipw  = (const float*)d_in[8];
  const float* ipb  = (const float*)d_in[9];
  const float* opw  = (const float*)d_in[10];
  const float* opb  = (const float*)d_in[11];
  const float* w2   = (const float*)d_in[12];
  const float* b2   = (const float*)d_in[13];
  const float* g2   = (const float*)d_in[14];
  const float* be2  = (const float*)d_in[15];
  const float* mu2  = (const float*)d_in[16];
  const float* va2  = (const float*)d_in[17];
  const float* w3   = (const float*)d_in[18];
  const float* b3   = (const float*)d_in[19];
  const float* g3   = (const float*)d_in[20];
  const float* be3  = (const float*)d_in[21];
  const float* mu3  = (const float*)d_in[22];
  const float* va3  = (const float*)d_in[23];
  const float* w4   = (const float*)d_in[24];
  const float* b4   = (const float*)d_in[25];

  char* ws = (char*)d_ws;
  float* x    = (float*)(ws);                 // 1 MB : (B*S, E)
  float* qkv  = (float*)(ws + 1048576);       // 3 MB : (B*S, 768)
  float* ctx  = (float*)(ws + 4194304);       // 1 MB : (B*S, E)
  float* attn = (float*)(ws + 5242880);       // 1 MB : (B*S, E)
  int*   ids  = (int*)  (ws + 6291456);       // 256 KB : (N,)
  float* out  = (float*)d_out;                // (B, 2, N)

  build_ids_k<<<1, 256, 0, stream>>>(npc, ids);
  pos_x_k<<<B_ * S_, 256, 0, stream>>>(gl, cen, fc1w, fc1b, fc2w, fc2b, x);
  gemm64_k<<<dim3(16, 12), 256, 0, stream>>>(x, ipw, ipb, qkv, B_ * S_, 768, E_);
  attn_k<<<B_ * H_ * 4, 256, 0, stream>>>(qkv, ctx);
  gemm64_k<<<dim3(16, 4), 256, 0, stream>>>(ctx, opw, opb, attn, B_ * S_, E_, E_);
  conv_fused_k<<<B_ * (N_ / 64), 256, 0, stream>>>(
      lo, attn, ids, w2, b2, g2, be2, mu2, va2,
      w3, b3, g3, be3, mu3, va3, w4, b4, out);
}

// Round 2
// 397.044 us; speedup vs baseline: 3.2318x; 3.2318x over previous
//
#include <hip/hip_runtime.h>

#define B_   4
#define S_   256
#define E_   256
#define H_   8
#define LD_  128
#define N_   65536
#define NC_  2
#define PK   68   // fp32 gemm64 padding (unchanged)

typedef __attribute__((ext_vector_type(8))) short s8v;   // 8 bf16 (4 VGPRs)
typedef __attribute__((ext_vector_type(4))) float f32x4;

__device__ __forceinline__ short f2bf(float f) {
  union { float f; unsigned u; } v; v.f = f;
  unsigned r = (v.u + 0x7FFFu + ((v.u >> 16) & 1u)) >> 16;   // RNE
  return (short)r;
}
__device__ __forceinline__ float bf2f(short s) {
  union { float f; unsigned u; } v; v.u = ((unsigned)(unsigned short)s) << 16;
  return v.f;
}

// ---------------------------------------------------------------------------
// K0: cluster ids
// ---------------------------------------------------------------------------
__global__ __launch_bounds__(256) void build_ids_k(const int* __restrict__ npc,
                                                   int* __restrict__ ids) {
  __shared__ int pre[S_ + 1];
  int t = threadIdx.x;
  if (t == 0) {
    pre[0] = 0;
    for (int s = 0; s < S_; s++) pre[s + 1] = pre[s] + npc[s];
  }
  __syncthreads();
  for (int n = t; n < N_; n += 256) ids[n] = S_ - 1;
  __syncthreads();
  int s = t;
  int st = pre[s];
  int en = pre[s + 1]; if (en > N_) en = N_;
  for (int n = st; n < en; n++) ids[n] = s;
}

// ---------------------------------------------------------------------------
// K0b: pre-convert w2/w3 to bf16
// ---------------------------------------------------------------------------
__global__ __launch_bounds__(256) void cvt_w_k(const float* __restrict__ w2,
                                               const float* __restrict__ w3,
                                               short* __restrict__ w2bf,
                                               short* __restrict__ w3bf) {
  int i = blockIdx.x * 256 + threadIdx.x;
  if (i < 128 * 384) w2bf[i] = f2bf(w2[i]);
  if (i < 64 * 128)  w3bf[i] = f2bf(w3[i]);
}

// ---------------------------------------------------------------------------
// K1: pos-MLP + add gl_feats^T  ->  x[b][s][e]
// ---------------------------------------------------------------------------
__global__ __launch_bounds__(256) void pos_x_k(const float* __restrict__ gl,
                                               const float* __restrict__ cen,
                                               const float* __restrict__ fc1w,
                                               const float* __restrict__ fc1b,
                                               const float* __restrict__ fc2w,
                                               const float* __restrict__ fc2b,
                                               float* __restrict__ x) {
  int bs = blockIdx.x;
  int b = bs >> 8, s = bs & 255;
  __shared__ float hsh[16];
  int t = threadIdx.x;
  if (t < 16) {
    float c0 = cen[bs * 2 + 0], c1 = cen[bs * 2 + 1];
    float v = c0 * fc1w[2 * t] + c1 * fc1w[2 * t + 1] + fc1b[t];
    hsh[t] = (v >= 0.f) ? v : 0.01f * v;
  }
  __syncthreads();
  float p = fc2b[t];
#pragma unroll
  for (int j = 0; j < 16; j++) p += hsh[j] * fc2w[t * 16 + j];
  x[(size_t)bs * E_ + t] = gl[((size_t)s * B_ + b) * E_ + t] + p;
}

// ---------------------------------------------------------------------------
// K2/K4: fp32 GEMM (unchanged this round)
// ---------------------------------------------------------------------------
__global__ __launch_bounds__(256) void gemm64_k(const float* __restrict__ A,
                                                const float* __restrict__ W,
                                                const float* __restrict__ bias,
                                                float* __restrict__ C,
                                                int M, int N, int K) {
  __shared__ __align__(16) float sA[64 * PK];
  __shared__ __align__(16) float sW[64 * PK];
  int t = threadIdx.x;
  int row0 = blockIdx.x * 64, col0 = blockIdx.y * 64;
  int tp = t & 15, tc = t >> 4;
  int srow = t >> 4, sk4 = (t & 15) * 4;
  float acc[4][4];
#pragma unroll
  for (int i = 0; i < 4; i++)
#pragma unroll
    for (int j = 0; j < 4; j++) acc[i][j] = 0.f;

  for (int kc = 0; kc < K; kc += 64) {
    __syncthreads();
#pragma unroll
    for (int i = 0; i < 4; i++) {
      int r = i * 16 + srow;
      *(float4*)&sA[r * PK + sk4] = *(const float4*)&A[(size_t)(row0 + r) * K + kc + sk4];
      *(float4*)&sW[r * PK + sk4] = *(const float4*)&W[(size_t)(col0 + r) * K + kc + sk4];
    }
    __syncthreads();
#pragma unroll
    for (int k4 = 0; k4 < 64; k4 += 4) {
      float4 a[4], w[4];
#pragma unroll
      for (int i = 0; i < 4; i++) a[i] = *(const float4*)&sA[(4 * tp + i) * PK + k4];
#pragma unroll
      for (int i = 0; i < 4; i++) w[i] = *(const float4*)&sW[(4 * tc + i) * PK + k4];
#pragma unroll
      for (int pi = 0; pi < 4; pi++)
#pragma unroll
        for (int ci = 0; ci < 4; ci++)
          acc[pi][ci] += a[pi].x * w[ci].x + a[pi].y * w[ci].y +
                         a[pi].z * w[ci].z + a[pi].w * w[ci].w;
    }
  }
#pragma unroll
  for (int pi = 0; pi < 4; pi++) {
    int r = row0 + 4 * tp + pi;
    int c = col0 + 4 * tc;
    float4 o;
    o.x = acc[pi][0] + bias[c + 0];
    o.y = acc[pi][1] + bias[c + 1];
    o.z = acc[pi][2] + bias[c + 2];
    o.w = acc[pi][3] + bias[c + 3];
    *(float4*)&C[(size_t)r * N + c] = o;
  }
}

// ---------------------------------------------------------------------------
// K3: attention (unchanged this round)
// ---------------------------------------------------------------------------
__global__ __launch_bounds__(256) void attn_k(const float* __restrict__ qkv,
                                              float* __restrict__ ctxo) {
  int bid = blockIdx.x;
  int qt = bid & 3, h = (bid >> 2) & 7, b = bid >> 5;
  __shared__ __align__(16) float smem[16384];
  float* Kx = smem;
  float* Vx = smem + 8192;
  int t = threadIdx.x;
#pragma unroll
  for (int i = 0; i < 8; i++) {
    int row = i * 32 + (t >> 3);
    int d4 = (t & 7) * 4;
    const float* base = qkv + (size_t)(b * S_ + row) * 768 + h * 32 + d4;
    *(float4*)&Kx[row * 32 + d4] = *(const float4*)(base + 256);
    *(float4*)&Vx[row * 32 + d4] = *(const float4*)(base + 512);
  }
  int r = t & 63, g = t >> 6;
  float q[32];
  {
    const float* qb = qkv + (size_t)(b * S_ + qt * 64 + r) * 768 + h * 32;
#pragma unroll
    for (int d4 = 0; d4 < 32; d4 += 4) {
      float4 v = *(const float4*)(qb + d4);
      q[d4] = v.x; q[d4 + 1] = v.y; q[d4 + 2] = v.z; q[d4 + 3] = v.w;
    }
  }
  __syncthreads();
  const float scale = 0.17677669529663687f;
  int kk0 = g * 64;
  float m = -1e30f;
  for (int kk = kk0; kk < kk0 + 64; kk++) {
    const float* kr = &Kx[kk * 32];
    float s = 0.f;
#pragma unroll
    for (int d4 = 0; d4 < 32; d4 += 4) {
      float4 kv = *(const float4*)(kr + d4);
      s += q[d4] * kv.x + q[d4 + 1] * kv.y + q[d4 + 2] * kv.z + q[d4 + 3] * kv.w;
    }
    m = fmaxf(m, s * scale);
  }
  float l = 0.f;
  float ctx[32];
#pragma unroll
  for (int d = 0; d < 32; d++) ctx[d] = 0.f;
  for (int kk = kk0; kk < kk0 + 64; kk++) {
    const float* kr = &Kx[kk * 32];
    const float* vr = &Vx[kk * 32];
    float s = 0.f;
#pragma unroll
    for (int d4 = 0; d4 < 32; d4 += 4) {
      float4 kv = *(const float4*)(kr + d4);
      s += q[d4] * kv.x + q[d4 + 1] * kv.y + q[d4 + 2] * kv.z + q[d4 + 3] * kv.w;
    }
    float p = __expf(s * scale - m);
    l += p;
#pragma unroll
    for (int d4 = 0; d4 < 32; d4 += 4) {
      float4 vv = *(const float4*)(vr + d4);
      ctx[d4] += p * vv.x; ctx[d4 + 1] += p * vv.y;
      ctx[d4 + 2] += p * vv.z; ctx[d4 + 3] += p * vv.w;
    }
  }
  __syncthreads();
  float* ctxbuf = smem;
  float* mbuf = smem + 8192;
  float* lbuf = smem + 8192 + 256;
  mbuf[g * 64 + r] = m;
  lbuf[g * 64 + r] = l;
#pragma unroll
  for (int d = 0; d < 32; d++)
    ctxbuf[(g * 64 + r) * 32 + ((d + r) & 31)] = ctx[d];
  __syncthreads();
  int r2 = t & 63, dq = t >> 6;
  float M = fmaxf(fmaxf(mbuf[r2], mbuf[64 + r2]), fmaxf(mbuf[128 + r2], mbuf[192 + r2]));
  float wg[4]; float L = 0.f;
#pragma unroll
  for (int gg = 0; gg < 4; gg++) {
    wg[gg] = __expf(mbuf[gg * 64 + r2] - M);
    L += lbuf[gg * 64 + r2] * wg[gg];
  }
  float invL = 1.f / L;
  float* orow = ctxo + (size_t)(b * S_ + qt * 64 + r2) * E_ + h * 32;
#pragma unroll
  for (int dd = 0; dd < 8; dd++) {
    int d = dq * 8 + dd;
    float o = 0.f;
#pragma unroll
    for (int gg = 0; gg < 4; gg++)
      o += ctxbuf[(gg * 64 + r2) * 32 + ((d + r2) & 31)] * wg[gg];
    orow[d] = o * invL;
  }
}

// ---------------------------------------------------------------------------
// K5: fused conv2+bn2+relu -> conv3+bn3+relu -> conv4 with bf16 MFMA.
// Block = 128 points, 4 waves. conv2: wave = 64 points x 64 ch (mt=4,ct=4).
// conv3: wave = 32 points x 64 ch (mt=2,ct=4). conv4 fp32 VALU.
// LDS strides: SA/SW 72 (2-way, free), h2/SW3 136 (2-way reads), h3 72.
// Total LDS 52224 B -> 3 blocks/CU.
// ---------------------------------------------------------------------------
#define SA_OFF   0        // [128][72] shorts
#define SW_OFF   9216     // [128][72]
#define H2_OFF   0        // [128][136] (over SA+SW after conv2)
#define SW3_OFF  17408    // [64][136]
#define H3_OFF   0        // [128][72] (over h2 after conv3)

__global__ __launch_bounds__(256, 3) void conv_fused_k(
    const float* __restrict__ lo, const float* __restrict__ attn,
    const int* __restrict__ ids,
    const short* __restrict__ w2bf,
    const float* __restrict__ b2,
    const float* __restrict__ g2, const float* __restrict__ be2,
    const float* __restrict__ mu2, const float* __restrict__ va2,
    const short* __restrict__ w3bf,
    const float* __restrict__ b3,
    const float* __restrict__ g3, const float* __restrict__ be3,
    const float* __restrict__ mu3, const float* __restrict__ va3,
    const float* __restrict__ w4, const float* __restrict__ b4,
    float* __restrict__ out) {
  __shared__ __align__(16) short smem[26112];  // 52224 B
  int t = threadIdx.x;
  int bid = blockIdx.x;
  int b = bid >> 9;
  int n0 = (bid & 511) << 7;          // 128 points per block
  int w = t >> 6, l = t & 63;
  int quad = l >> 4, lr = l & 15;
  int mh = w & 1, chh = w >> 1;       // conv2 wave partition

  f32x4 acc2[4][4];
#pragma unroll
  for (int i = 0; i < 4; i++)
#pragma unroll
    for (int j = 0; j < 4; j++) acc2[i][j] = (f32x4)(0.f);

  // ---- conv2: K = 384 in 6 chunks of 64
  int ar = t >> 1;                    // staging row 0..127
  int akh = (t & 1) * 32;             // k-half
  for (int kc = 0; kc < 6; kc++) {
    __syncthreads();
    {  // A stage: 128 points x 64 k, fp32 -> bf16
      const float* src;
      if (kc < 2) src = &lo[((size_t)b * N_ + n0 + ar) * LD_ + kc * 64 + akh];
      else        src = &attn[((size_t)b * S_ + ids[n0 + ar]) * E_ + (kc - 2) * 64 + akh];
#pragma unroll
      for (int j = 0; j < 4; j++) {
        float4 v0 = *(const float4*)(src + j * 8);
        float4 v1 = *(const float4*)(src + j * 8 + 4);
        s8v pk;
        pk[0] = f2bf(v0.x); pk[1] = f2bf(v0.y); pk[2] = f2bf(v0.z); pk[3] = f2bf(v0.w);
        pk[4] = f2bf(v1.x); pk[5] = f2bf(v1.y); pk[6] = f2bf(v1.z); pk[7] = f2bf(v1.w);
        *(s8v*)&smem[SA_OFF + ar * 72 + akh + j * 8] = pk;
      }
    }
    {  // W stage: 128 ch x 64 k bf16 from pre-converted global
      const s8v* src = (const s8v*)&w2bf[ar * 384 + kc * 64 + akh];
      s8v* dst = (s8v*)&smem[SW_OFF + ar * 72 + akh];
#pragma unroll
      for (int j = 0; j < 4; j++) dst[j] = src[j];
    }
    __syncthreads();
#pragma unroll
    for (int ks = 0; ks < 2; ks++) {
      s8v af[4], bf[4];
#pragma unroll
      for (int mt = 0; mt < 4; mt++)
        af[mt] = *(const s8v*)&smem[SA_OFF + (64 * mh + 16 * mt + lr) * 72 + ks * 32 + quad * 8];
#pragma unroll
      for (int ct = 0; ct < 4; ct++)
        bf[ct] = *(const s8v*)&smem[SW_OFF + (64 * chh + 16 * ct + lr) * 72 + ks * 32 + quad * 8];
#pragma unroll
      for (int mt = 0; mt < 4; mt++)
#pragma unroll
        for (int ct = 0; ct < 4; ct++)
          acc2[mt][ct] = __builtin_amdgcn_mfma_f32_16x16x32_bf16(af[mt], bf[ct], acc2[mt][ct], 0, 0, 0);
    }
  }
  __syncthreads();  // SA/SW dead

  // ---- bn2 + relu -> h2 (bf16, [128][136]); also stage w3 into SW3
#pragma unroll
  for (int ct = 0; ct < 4; ct++) {
    int c = 64 * chh + 16 * ct + lr;
    float sc = g2[c] * rsqrtf(va2[c] + 1e-5f);
    float sh = be2[c] - mu2[c] * sc;
    float bb = b2[c];
#pragma unroll
    for (int mt = 0; mt < 4; mt++)
#pragma unroll
      for (int rg = 0; rg < 4; rg++) {
        int p = 64 * mh + 16 * mt + 4 * quad + rg;
        float z = (acc2[mt][ct][rg] + bb) * sc + sh;
        smem[H2_OFF + p * 136 + c] = f2bf(fmaxf(z, 0.f));
      }
  }
  {  // SW3 stage: 64 ch x 128 k
    int ch = t >> 2, kq = (t & 3) * 32;
    const s8v* src = (const s8v*)&w3bf[ch * 128 + kq];
    s8v* dst = (s8v*)&smem[SW3_OFF + ch * 136 + kq];
#pragma unroll
    for (int j = 0; j < 4; j++) dst[j] = src[j];
  }
  __syncthreads();

  // ---- conv3: 128 points x 64 ch, K = 128. wave = 32 points (mt=2) x 64 ch (ct=4)
  f32x4 acc3[2][4];
#pragma unroll
  for (int i = 0; i < 2; i++)
#pragma unroll
    for (int j = 0; j < 4; j++) acc3[i][j] = (f32x4)(0.f);
#pragma unroll
  for (int ks = 0; ks < 4; ks++) {
    s8v af[2], bf[4];
#pragma unroll
    for (int mt = 0; mt < 2; mt++)
      af[mt] = *(const s8v*)&smem[H2_OFF + (32 * w + 16 * mt + lr) * 136 + ks * 32 + quad * 8];
#pragma unroll
    for (int ct = 0; ct < 4; ct++)
      bf[ct] = *(const s8v*)&smem[SW3_OFF + (16 * ct + lr) * 136 + ks * 32 + quad * 8];
#pragma unroll
    for (int mt = 0; mt < 2; mt++)
#pragma unroll
      for (int ct = 0; ct < 4; ct++)
        acc3[mt][ct] = __builtin_amdgcn_mfma_f32_16x16x32_bf16(af[mt], bf[ct], acc3[mt][ct], 0, 0, 0);
  }
  __syncthreads();  // h2 dead

  // ---- bn3 + relu -> h3 (bf16, [128][72])
#pragma unroll
  for (int ct = 0; ct < 4; ct++) {
    int c = 16 * ct + lr;
    float sc = g3[c] * rsqrtf(va3[c] + 1e-5f);
    float sh = be3[c] - mu3[c] * sc;
    float bb = b3[c];
#pragma unroll
    for (int mt = 0; mt < 2; mt++)
#pragma unroll
      for (int rg = 0; rg < 4; rg++) {
        int p = 32 * w + 16 * mt + 4 * quad + rg;
        float z = (acc3[mt][ct][rg] + bb) * sc + sh;
        smem[H3_OFF + p * 72 + c] = f2bf(fmaxf(z, 0.f));
      }
  }
  __syncthreads();

  // ---- conv4 (fp32): out[b][c][n], c in {0,1}, K = 64
  {
    int c = t >> 7, p = t & 127;
    float s = b4[c];
#pragma unroll
    for (int j = 0; j < 8; j++) {
      s8v hv = *(const s8v*)&smem[H3_OFF + p * 72 + j * 8];
#pragma unroll
      for (int e = 0; e < 8; e++)
        s += bf2f(hv[e]) * w4[c * 64 + j * 8 + e];
    }
    out[((size_t)b * NC_ + c) * N_ + n0 + p] = s;
  }
}

// ---------------------------------------------------------------------------
extern "C" void kernel_launch(void* const* d_in, const int* in_sizes, int n_in,
                              void* d_out, int out_size, void* d_ws, size_t ws_size,
                              hipStream_t stream) {
  const float* gl   = (const float*)d_in[0];
  const float* lo   = (const float*)d_in[1];
  const float* cen  = (const float*)d_in[2];
  const int*   npc  = (const int*)d_in[3];
  const float* fc1w = (const float*)d_in[4];
  const float* fc1b = (const float*)d_in[5];
  const float* fc2w = (const float*)d_in[6];
  const float* fc2b = (const float*)d_in[7];
  const float* ipw  = (const float*)d_in[8];
  const float* ipb  = (const float*)d_in[9];
  const float* opw  = (const float*)d_in[10];
  const float* opb  = (const float*)d_in[11];
  const float* w2   = (const float*)d_in[12];
  const float* b2   = (const float*)d_in[13];
  const float* g2   = (const float*)d_in[14];
  const float* be2  = (const float*)d_in[15];
  const float* mu2  = (const float*)d_in[16];
  const float* va2  = (const float*)d_in[17];
  const float* w3   = (const float*)d_in[18];
  const float* b3   = (const float*)d_in[19];
  const float* g3   = (const float*)d_in[20];
  const float* be3  = (const float*)d_in[21];
  const float* mu3  = (const float*)d_in[22];
  const float* va3  = (const float*)d_in[23];
  const float* w4   = (const float*)d_in[24];
  const float* b4   = (const float*)d_in[25];

  char* ws = (char*)d_ws;
  float* x    = (float*)(ws);                 // 1 MB
  float* qkv  = (float*)(ws + 1048576);       // 3 MB
  float* ctx  = (float*)(ws + 4194304);       // 1 MB
  float* attn = (float*)(ws + 5242880);       // 1 MB
  int*   ids  = (int*)  (ws + 6291456);       // 256 KB
  short* w2bf = (short*)(ws + 6553600);       // 96 KB
  short* w3bf = (short*)(ws + 6651904);       // 16 KB
  float* out  = (float*)d_out;

  cvt_w_k<<<192, 256, 0, stream>>>(w2, w3, w2bf, w3bf);
  build_ids_k<<<1, 256, 0, stream>>>(npc, ids);
  pos_x_k<<<B_ * S_, 256, 0, stream>>>(gl, cen, fc1w, fc1b, fc2w, fc2b, x);
  gemm64_k<<<dim3(16, 12), 256, 0, stream>>>(x, ipw, ipb, qkv, B_ * S_, 768, E_);
  attn_k<<<B_ * H_ * 4, 256, 0, stream>>>(qkv, ctx);
  gemm64_k<<<dim3(16, 4), 256, 0, stream>>>(ctx, opw, opb, attn, B_ * S_, E_, E_);
  conv_fused_k<<<B_ * (N_ / 128), 256, 0, stream>>>(
      lo, attn, ids, w2bf, b2, g2, be2, mu2, va2,
      w3bf, b3, g3, be3, mu3, va3, w4, b4, out);
}

// Round 3
// 317.804 us; speedup vs baseline: 4.0376x; 1.2493x over previous
//
#include <hip/hip_runtime.h>

#define B_   4
#define S_   256
#define E_   256
#define H_   8
#define LD_  128
#define N_   65536
#define NC_  2

typedef __attribute__((ext_vector_type(8))) short s8v;   // 8 bf16
typedef __attribute__((ext_vector_type(4))) float f32x4;

__device__ __forceinline__ short f2bf(float f) {
  union { float f; unsigned u; } v; v.f = f;
  unsigned r = (v.u + 0x7FFFu + ((v.u >> 16) & 1u)) >> 16;   // RNE
  return (short)r;
}
__device__ __forceinline__ float bf2f(short s) {
  union { float f; unsigned u; } v; v.u = ((unsigned)(unsigned short)s) << 16;
  return v.f;
}
__device__ __forceinline__ s8v pack8(float4 a, float4 b) {
  s8v r;
  r[0] = f2bf(a.x); r[1] = f2bf(a.y); r[2] = f2bf(a.z); r[3] = f2bf(a.w);
  r[4] = f2bf(b.x); r[5] = f2bf(b.y); r[6] = f2bf(b.z); r[7] = f2bf(b.w);
  return r;
}

// ---------------------------------------------------------------------------
// ids: prefix then parallel coalesced fill
// ---------------------------------------------------------------------------
__global__ __launch_bounds__(256) void ids_pre_k(const int* __restrict__ npc,
                                                 int* __restrict__ pre) {
  __shared__ int ps[257];
  int t = threadIdx.x;
  if (t == 0) {
    ps[0] = 0;
    for (int s = 0; s < 256; s++) ps[s + 1] = ps[s] + npc[s];
  }
  __syncthreads();
  pre[t] = ps[t];
  if (t == 0) pre[256] = ps[256];
}

__global__ __launch_bounds__(256) void ids_fill_k(const int* __restrict__ pre,
                                                  int* __restrict__ ids) {
  int s = blockIdx.x, t = threadIdx.x;
  if (s < 256) {
    int st = pre[s], en = pre[s + 1]; if (en > N_) en = N_;
    for (int n = st + t; n < en; n += 256) ids[n] = s;
  } else {
    int st = pre[256];
    for (int n = st + t; n < N_; n += 256) ids[n] = 255;
  }
}

// ---------------------------------------------------------------------------
// weight prep: hi/lo split for ipw/opw, bf16 for w2/w3, folded bn consts
// ---------------------------------------------------------------------------
__global__ __launch_bounds__(256) void cvt_w_k(
    const float* __restrict__ ipw, const float* __restrict__ opw,
    const float* __restrict__ w2, const float* __restrict__ w3,
    const float* __restrict__ b2, const float* __restrict__ g2,
    const float* __restrict__ be2, const float* __restrict__ mu2,
    const float* __restrict__ va2,
    const float* __restrict__ b3, const float* __restrict__ g3,
    const float* __restrict__ be3, const float* __restrict__ mu3,
    const float* __restrict__ va3,
    short* __restrict__ iph, short* __restrict__ ipl,
    short* __restrict__ oph, short* __restrict__ opl,
    short* __restrict__ w2bf, short* __restrict__ w3bf,
    float* __restrict__ sc2, float* __restrict__ sh2,
    float* __restrict__ sc3, float* __restrict__ sh3) {
  int i = blockIdx.x * 256 + threadIdx.x;
  if (i < 196608) {
    float v = ipw[i]; short h = f2bf(v);
    iph[i] = h; ipl[i] = f2bf(v - bf2f(h));
  }
  if (i < 65536) {
    float v = opw[i]; short h = f2bf(v);
    oph[i] = h; opl[i] = f2bf(v - bf2f(h));
  }
  if (i < 49152) w2bf[i] = f2bf(w2[i]);
  if (i < 8192)  w3bf[i] = f2bf(w3[i]);
  if (i < 128) {
    float sc = g2[i] * rsqrtf(va2[i] + 1e-5f);
    sc2[i] = sc; sh2[i] = (b2[i] - mu2[i]) * sc + be2[i];
  }
  if (i < 64) {
    float sc = g3[i] * rsqrtf(va3[i] + 1e-5f);
    sc3[i] = sc; sh3[i] = (b3[i] - mu3[i]) * sc + be3[i];
  }
}

// ---------------------------------------------------------------------------
// pos-MLP + add gl^T -> x, emitted as hi/lo bf16 planes
// ---------------------------------------------------------------------------
__global__ __launch_bounds__(256) void pos_x_k(const float* __restrict__ gl,
                                               const float* __restrict__ cen,
                                               const float* __restrict__ fc1w,
                                               const float* __restrict__ fc1b,
                                               const float* __restrict__ fc2w,
                                               const float* __restrict__ fc2b,
                                               short* __restrict__ Xhi,
                                               short* __restrict__ Xlo) {
  int bs = blockIdx.x;
  int b = bs >> 8, s = bs & 255;
  __shared__ float hsh[16];
  int t = threadIdx.x;
  if (t < 16) {
    float c0 = cen[bs * 2 + 0], c1 = cen[bs * 2 + 1];
    float v = c0 * fc1w[2 * t] + c1 * fc1w[2 * t + 1] + fc1b[t];
    hsh[t] = (v >= 0.f) ? v : 0.01f * v;
  }
  __syncthreads();
  float p = fc2b[t];
#pragma unroll
  for (int j = 0; j < 16; j++) p += hsh[j] * fc2w[t * 16 + j];
  float v = gl[((size_t)s * B_ + b) * E_ + t] + p;
  short h = f2bf(v);
  Xhi[(size_t)bs * E_ + t] = h;
  Xlo[(size_t)bs * E_ + t] = f2bf(v - bf2f(h));
}

// ---------------------------------------------------------------------------
// bf16x3 MFMA GEMM: C = (Ah+Al)(Wh+Wl)^T + bias  (A_lo*W_lo dropped)
// 64x64 tile, BK=64, 4 waves, wave = 16-row strip x 64 cols
// ---------------------------------------------------------------------------
__global__ __launch_bounds__(256) void gemm_x3_k(
    const short* __restrict__ Ah, const short* __restrict__ Al,
    const short* __restrict__ Wh, const short* __restrict__ Wl,
    const float* __restrict__ bias, float* __restrict__ Cf,
    short* __restrict__ Cb, int M, int N, int K) {
  __shared__ __align__(16) short gs[18432];   // 4 x [64][72]
  const int AH = 0, AL = 4608, WH = 9216, WL = 13824;
  int t = threadIdx.x;
  int row0 = blockIdx.x * 64, col0 = blockIdx.y * 64;
  int w = t >> 6, l = t & 63, quad = l >> 4, lr = l & 15;
  int m0 = w * 16;
  int ar = t >> 2, aq = (t & 3) * 16;
  f32x4 acc[4];
#pragma unroll
  for (int i = 0; i < 4; i++) acc[i] = (f32x4)(0.f);

  for (int kc = 0; kc < K; kc += 64) {
    __syncthreads();
    {
      size_t ra = (size_t)(row0 + ar) * K + kc + aq;
      size_t rw = (size_t)(col0 + ar) * K + kc + aq;
      *(s8v*)&gs[AH + ar * 72 + aq]     = *(const s8v*)&Ah[ra];
      *(s8v*)&gs[AH + ar * 72 + aq + 8] = *(const s8v*)&Ah[ra + 8];
      *(s8v*)&gs[AL + ar * 72 + aq]     = *(const s8v*)&Al[ra];
      *(s8v*)&gs[AL + ar * 72 + aq + 8] = *(const s8v*)&Al[ra + 8];
      *(s8v*)&gs[WH + ar * 72 + aq]     = *(const s8v*)&Wh[rw];
      *(s8v*)&gs[WH + ar * 72 + aq + 8] = *(const s8v*)&Wh[rw + 8];
      *(s8v*)&gs[WL + ar * 72 + aq]     = *(const s8v*)&Wl[rw];
      *(s8v*)&gs[WL + ar * 72 + aq + 8] = *(const s8v*)&Wl[rw + 8];
    }
    __syncthreads();
#pragma unroll
    for (int ks = 0; ks < 2; ks++) {
      int ko = ks * 32 + quad * 8;
      s8v ah = *(const s8v*)&gs[AH + (m0 + lr) * 72 + ko];
      s8v al = *(const s8v*)&gs[AL + (m0 + lr) * 72 + ko];
      s8v bh[4], bl[4];
#pragma unroll
      for (int ct = 0; ct < 4; ct++) {
        bh[ct] = *(const s8v*)&gs[WH + (ct * 16 + lr) * 72 + ko];
        bl[ct] = *(const s8v*)&gs[WL + (ct * 16 + lr) * 72 + ko];
      }
#pragma unroll
      for (int ct = 0; ct < 4; ct++) {
        acc[ct] = __builtin_amdgcn_mfma_f32_16x16x32_bf16(ah, bh[ct], acc[ct], 0, 0, 0);
        acc[ct] = __builtin_amdgcn_mfma_f32_16x16x32_bf16(al, bh[ct], acc[ct], 0, 0, 0);
        acc[ct] = __builtin_amdgcn_mfma_f32_16x16x32_bf16(ah, bl[ct], acc[ct], 0, 0, 0);
      }
    }
  }
#pragma unroll
  for (int ct = 0; ct < 4; ct++) {
    int c = col0 + ct * 16 + lr;
    float bb = bias[c];
#pragma unroll
    for (int rg = 0; rg < 4; rg++) {
      int r = row0 + m0 + quad * 4 + rg;
      float v = acc[ct][rg] + bb;
      if (Cb) Cb[(size_t)r * N + c] = f2bf(v);
      else    Cf[(size_t)r * N + c] = v;
    }
  }
}

// ---------------------------------------------------------------------------
// attention: 256 blocks = (b, h, 32-row q-tile); 8 k-groups of 32; scores in
// regs (single K pass); split-K softmax merge in LDS; ctx out as hi/lo bf16
// ---------------------------------------------------------------------------
__global__ __launch_bounds__(256) void attn_k(const float* __restrict__ qkv,
                                              short* __restrict__ Chi,
                                              short* __restrict__ Clo) {
  int bid = blockIdx.x;
  int qt = bid & 7, h = (bid >> 3) & 7, b = bid >> 6;
  __shared__ __align__(16) float smem[16384];
  float* Kx = smem;          // [256][32]
  float* Vx = smem + 8192;   // [256][32]
  int t = threadIdx.x;
#pragma unroll
  for (int i = 0; i < 8; i++) {
    int row = i * 32 + (t >> 3);
    int d4 = (t & 7) * 4;
    const float* base = qkv + (size_t)(b * S_ + row) * 768 + h * 32 + d4;
    *(float4*)&Kx[row * 32 + d4] = *(const float4*)(base + 256);
    *(float4*)&Vx[row * 32 + d4] = *(const float4*)(base + 512);
  }
  int r = t & 31, g = t >> 5;
  float q[32];
  {
    const float* qb = qkv + (size_t)(b * S_ + qt * 32 + r) * 768 + h * 32;
#pragma unroll
    for (int d4 = 0; d4 < 32; d4 += 4) {
      float4 v = *(const float4*)(qb + d4);
      q[d4] = v.x; q[d4 + 1] = v.y; q[d4 + 2] = v.z; q[d4 + 3] = v.w;
    }
  }
  __syncthreads();
  const float scale = 0.17677669529663687f;
  int kk0 = g * 32;
  float sc[32];
  float m = -1e30f;
#pragma unroll
  for (int kk = 0; kk < 32; kk++) {
    const float* kr = &Kx[(kk0 + kk) * 32];
    float4 a = (float4){0.f, 0.f, 0.f, 0.f};
#pragma unroll
    for (int d4 = 0; d4 < 32; d4 += 4) {
      float4 kv = *(const float4*)(kr + d4);
      a.x += q[d4] * kv.x; a.y += q[d4 + 1] * kv.y;
      a.z += q[d4 + 2] * kv.z; a.w += q[d4 + 3] * kv.w;
    }
    float s = ((a.x + a.y) + (a.z + a.w)) * scale;
    sc[kk] = s;
    m = fmaxf(m, s);
  }
  float lsum = 0.f;
  float ctx[32];
#pragma unroll
  for (int d = 0; d < 32; d++) ctx[d] = 0.f;
#pragma unroll
  for (int kk = 0; kk < 32; kk++) {
    const float* vr = &Vx[(kk0 + kk) * 32];
    float p = __expf(sc[kk] - m);
    lsum += p;
#pragma unroll
    for (int d4 = 0; d4 < 32; d4 += 4) {
      float4 vv = *(const float4*)(vr + d4);
      ctx[d4] += p * vv.x; ctx[d4 + 1] += p * vv.y;
      ctx[d4 + 2] += p * vv.z; ctx[d4 + 3] += p * vv.w;
    }
  }
  __syncthreads();  // K/V dead
  float* ctxbuf = smem;            // [8*32][32] rotated
  float* mbuf = smem + 8192;       // [8*32]
  float* lbuf = smem + 8448;       // [8*32]
  mbuf[g * 32 + r] = m;
  lbuf[g * 32 + r] = lsum;
#pragma unroll
  for (int d = 0; d < 32; d++)
    ctxbuf[(g * 32 + r) * 32 + ((d + r) & 31)] = ctx[d];
  __syncthreads();
  int r2 = t & 31, dq = t >> 5;
  float M = -1e30f;
#pragma unroll
  for (int gg = 0; gg < 8; gg++) M = fmaxf(M, mbuf[gg * 32 + r2]);
  float wg[8]; float L = 0.f;
#pragma unroll
  for (int gg = 0; gg < 8; gg++) {
    wg[gg] = __expf(mbuf[gg * 32 + r2] - M);
    L += lbuf[gg * 32 + r2] * wg[gg];
  }
  float invL = 1.f / L;
  size_t base = (size_t)(b * S_ + qt * 32 + r2) * E_ + h * 32;
#pragma unroll
  for (int dd = 0; dd < 4; dd++) {
    int d = dq * 4 + dd;
    float o = 0.f;
#pragma unroll
    for (int gg = 0; gg < 8; gg++)
      o += ctxbuf[(gg * 32 + r2) * 32 + ((d + r2) & 31)] * wg[gg];
    o *= invL;
    short hi = f2bf(o);
    Chi[base + d] = hi;
    Clo[base + d] = f2bf(o - bf2f(hi));
  }
}

// ---------------------------------------------------------------------------
// fused conv2+bn2+relu -> conv3+bn3+relu -> conv4, bf16 MFMA, LDS
// double-buffered 1-barrier K-loop. Block = 128 points, 4 waves.
// LDS: SA0/SA1/SW0/SW1 [128][72] shorts each = 73728 B -> 2 blocks/CU.
// ---------------------------------------------------------------------------
#define H2O   0        // [128][136] shorts
#define SW3O  17408    // [64][136]
#define H3O   26112    // [128][72]

__global__ __launch_bounds__(256, 2) void conv_fused_k(
    const float* __restrict__ lo, const short* __restrict__ attnb,
    const int* __restrict__ ids,
    const short* __restrict__ w2bf, const short* __restrict__ w3bf,
    const float* __restrict__ sc2, const float* __restrict__ sh2,
    const float* __restrict__ sc3, const float* __restrict__ sh3,
    const float* __restrict__ w4, const float* __restrict__ b4,
    float* __restrict__ out) {
  __shared__ __align__(16) short smem[36864];  // 73728 B
  int t = threadIdx.x;
  int bid = blockIdx.x;
  int b = bid >> 9;
  int n0 = (bid & 511) << 7;
  int w = t >> 6, l = t & 63;
  int quad = l >> 4, lr = l & 15;
  int mh = w & 1, chh = w >> 1;

  int ar = t >> 1, akh = (t & 1) * 32;
  int sid = ids[n0 + ar];
  const float* lob = &lo[((size_t)b * N_ + n0 + ar) * LD_ + akh];
  const short* atb = &attnb[((size_t)b * S_ + sid) * E_ + akh];
  const short* wb  = &w2bf[ar * 384 + akh];
  int swr = ar * 72 + akh;

  f32x4 acc2[4][4];
#pragma unroll
  for (int i = 0; i < 4; i++)
#pragma unroll
    for (int j = 0; j < 4; j++) acc2[i][j] = (f32x4)(0.f);

  float4 pf[8]; s8v pa[4]; s8v pw[4];
  // prologue: stage chunk 0 (lo) into buf0
#pragma unroll
  for (int j = 0; j < 8; j++) pf[j] = *(const float4*)(lob + j * 4);
#pragma unroll
  for (int j = 0; j < 4; j++) pw[j] = *(const s8v*)(wb + j * 8);
#pragma unroll
  for (int j = 0; j < 4; j++)
    *(s8v*)&smem[swr + j * 8] = pack8(pf[2 * j], pf[2 * j + 1]);
#pragma unroll
  for (int j = 0; j < 4; j++) *(s8v*)&smem[18432 + swr + j * 8] = pw[j];
  __syncthreads();

  for (int kc = 0; kc < 6; kc++) {
    int cb = kc & 1;
    int sa_c = cb * 9216, sw_c = 18432 + cb * 9216;
    int sa_n = (cb ^ 1) * 9216, sw_n = 18432 + (cb ^ 1) * 9216;
    int kn = kc + 1;
    // issue next chunk's global loads (consumed after MFMA below)
    if (kn < 6) {
      if (kn < 2) {
#pragma unroll
        for (int j = 0; j < 8; j++) pf[j] = *(const float4*)(lob + kn * 64 + j * 4);
      } else {
#pragma unroll
        for (int j = 0; j < 4; j++) pa[j] = *(const s8v*)(atb + (kn - 2) * 64 + j * 8);
      }
#pragma unroll
      for (int j = 0; j < 4; j++) pw[j] = *(const s8v*)(wb + kn * 64 + j * 8);
    }
    // MFMA on current buffer
#pragma unroll
    for (int ks = 0; ks < 2; ks++) {
      int ko = ks * 32 + quad * 8;
      s8v af[4], bf[4];
#pragma unroll
      for (int mt = 0; mt < 4; mt++)
        af[mt] = *(const s8v*)&smem[sa_c + (64 * mh + 16 * mt + lr) * 72 + ko];
#pragma unroll
      for (int ct = 0; ct < 4; ct++)
        bf[ct] = *(const s8v*)&smem[sw_c + (64 * chh + 16 * ct + lr) * 72 + ko];
#pragma unroll
      for (int mt = 0; mt < 4; mt++)
#pragma unroll
        for (int ct = 0; ct < 4; ct++)
          acc2[mt][ct] = __builtin_amdgcn_mfma_f32_16x16x32_bf16(af[mt], bf[ct], acc2[mt][ct], 0, 0, 0);
    }
    // write next chunk into other buffer
    if (kn < 6) {
      if (kn < 2) {
#pragma unroll
        for (int j = 0; j < 4; j++)
          *(s8v*)&smem[sa_n + swr + j * 8] = pack8(pf[2 * j], pf[2 * j + 1]);
      } else {
#pragma unroll
        for (int j = 0; j < 4; j++) *(s8v*)&smem[sa_n + swr + j * 8] = pa[j];
      }
#pragma unroll
      for (int j = 0; j < 4; j++) *(s8v*)&smem[sw_n + swr + j * 8] = pw[j];
    }
    __syncthreads();
  }

  // ---- bn2 + relu -> h2 ([128][136] bf16); stage w3 -> SW3
#pragma unroll
  for (int ct = 0; ct < 4; ct++) {
    int c = 64 * chh + 16 * ct + lr;
    float sc = sc2[c], sh = sh2[c];
#pragma unroll
    for (int mt = 0; mt < 4; mt++)
#pragma unroll
      for (int rg = 0; rg < 4; rg++) {
        int p = 64 * mh + 16 * mt + 4 * quad + rg;
        float z = acc2[mt][ct][rg] * sc + sh;
        smem[H2O + p * 136 + c] = f2bf(fmaxf(z, 0.f));
      }
  }
  {
    int ch = t >> 2, kq = (t & 3) * 32;
#pragma unroll
    for (int j = 0; j < 4; j++)
      *(s8v*)&smem[SW3O + ch * 136 + kq + j * 8] =
          *(const s8v*)&w3bf[ch * 128 + kq + j * 8];
  }
  __syncthreads();

  // ---- conv3: 128 pts x 64 ch, K=128; wave = 32 pts x 64 ch
  f32x4 acc3[2][4];
#pragma unroll
  for (int i = 0; i < 2; i++)
#pragma unroll
    for (int j = 0; j < 4; j++) acc3[i][j] = (f32x4)(0.f);
#pragma unroll
  for (int ks = 0; ks < 4; ks++) {
    int ko = ks * 32 + quad * 8;
    s8v af[2], bf[4];
#pragma unroll
    for (int mt = 0; mt < 2; mt++)
      af[mt] = *(const s8v*)&smem[H2O + (32 * w + 16 * mt + lr) * 136 + ko];
#pragma unroll
    for (int ct = 0; ct < 4; ct++)
      bf[ct] = *(const s8v*)&smem[SW3O + (16 * ct + lr) * 136 + ko];
#pragma unroll
    for (int mt = 0; mt < 2; mt++)
#pragma unroll
      for (int ct = 0; ct < 4; ct++)
        acc3[mt][ct] = __builtin_amdgcn_mfma_f32_16x16x32_bf16(af[mt], bf[ct], acc3[mt][ct], 0, 0, 0);
  }

  // ---- bn3 + relu -> h3 ([128][72], disjoint region: no barrier needed before)
#pragma unroll
  for (int ct = 0; ct < 4; ct++) {
    int c = 16 * ct + lr;
    float sc = sc3[c], sh = sh3[c];
#pragma unroll
    for (int mt = 0; mt < 2; mt++)
#pragma unroll
      for (int rg = 0; rg < 4; rg++) {
        int p = 32 * w + 16 * mt + 4 * quad + rg;
        float z = acc3[mt][ct][rg] * sc + sh;
        smem[H3O + p * 72 + c] = f2bf(fmaxf(z, 0.f));
      }
  }
  __syncthreads();

  // ---- conv4 (fp32): out[b][c][n0+p]
  {
    int c = t >> 7, p = t & 127;
    float s = b4[c];
#pragma unroll
    for (int j = 0; j < 8; j++) {
      s8v hv = *(const s8v*)&smem[H3O + p * 72 + j * 8];
#pragma unroll
      for (int e = 0; e < 8; e++)
        s += bf2f(hv[e]) * w4[c * 64 + j * 8 + e];
    }
    out[((size_t)b * NC_ + c) * N_ + n0 + p] = s;
  }
}

// ---------------------------------------------------------------------------
extern "C" void kernel_launch(void* const* d_in, const int* in_sizes, int n_in,
                              void* d_out, int out_size, void* d_ws, size_t ws_size,
                              hipStream_t stream) {
  const float* gl   = (const float*)d_in[0];
  const float* lo   = (const float*)d_in[1];
  const float* cen  = (const float*)d_in[2];
  const int*   npc  = (const int*)d_in[3];
  const float* fc1w = (const float*)d_in[4];
  const float* fc1b = (const float*)d_in[5];
  const float* fc2w = (const float*)d_in[6];
  const float* fc2b = (const float*)d_in[7];
  const float* ipw  = (const float*)d_in[8];
  const float* ipb  = (const float*)d_in[9];
  const float* opw  = (const float*)d_in[10];
  const float* opb  = (const float*)d_in[11];
  const float* w2   = (const float*)d_in[12];
  const float* b2   = (const float*)d_in[13];
  const float* g2   = (const float*)d_in[14];
  const float* be2  = (const float*)d_in[15];
  const float* mu2  = (const float*)d_in[16];
  const float* va2  = (const float*)d_in[17];
  const float* w3   = (const float*)d_in[18];
  const float* b3   = (const float*)d_in[19];
  const float* g3   = (const float*)d_in[20];
  const float* be3  = (const float*)d_in[21];
  const float* mu3  = (const float*)d_in[22];
  const float* va3  = (const float*)d_in[23];
  const float* w4   = (const float*)d_in[24];
  const float* b4   = (const float*)d_in[25];

  char* ws = (char*)d_ws;
  float* qkv  = (float*)(ws);                  // 3,145,728
  short* Xhi  = (short*)(ws + 3145728);        // 524,288
  short* Xlo  = (short*)(ws + 3670016);
  short* Chi  = (short*)(ws + 4194304);
  short* Clo  = (short*)(ws + 4718592);
  short* atb  = (short*)(ws + 5242880);        // attn_out bf16
  short* iph  = (short*)(ws + 5767168);        // 393,216
  short* ipl  = (short*)(ws + 6160384);
  short* oph  = (short*)(ws + 6553600);        // 131,072
  short* opl  = (short*)(ws + 6684672);
  short* w2bf = (short*)(ws + 6815744);        // 98,304
  short* w3bf = (short*)(ws + 6914048);        // 16,384
  int*   ids  = (int*)  (ws + 6930432);        // 262,144
  int*   pre  = (int*)  (ws + 7192576);        // 2,048 pad
  float* sc2  = (float*)(ws + 7194624);
  float* sh2  = (float*)(ws + 7195136);
  float* sc3  = (float*)(ws + 7195648);
  float* sh3  = (float*)(ws + 7195904);
  float* out  = (float*)d_out;

  cvt_w_k<<<768, 256, 0, stream>>>(ipw, opw, w2, w3, b2, g2, be2, mu2, va2,
                                   b3, g3, be3, mu3, va3,
                                   iph, ipl, oph, opl, w2bf, w3bf,
                                   sc2, sh2, sc3, sh3);
  ids_pre_k<<<1, 256, 0, stream>>>(npc, pre);
  ids_fill_k<<<257, 256, 0, stream>>>(pre, ids);
  pos_x_k<<<B_ * S_, 256, 0, stream>>>(gl, cen, fc1w, fc1b, fc2w, fc2b, Xhi, Xlo);
  gemm_x3_k<<<dim3(16, 12), 256, 0, stream>>>(Xhi, Xlo, iph, ipl, ipb,
                                              qkv, nullptr, B_ * S_, 768, E_);
  attn_k<<<B_ * H_ * 8, 256, 0, stream>>>(qkv, Chi, Clo);
  gemm_x3_k<<<dim3(16, 4), 256, 0, stream>>>(Chi, Clo, oph, opl, opb,
                                             nullptr, atb, B_ * S_, E_, E_);
  conv_fused_k<<<B_ * (N_ / 128), 256, 0, stream>>>(
      lo, atb, ids, w2bf, w3bf, sc2, sh2, sc3, sh3, w4, b4, out);
}

// Round 4
// 310.361 us; speedup vs baseline: 4.1345x; 1.0240x over previous
//
#include <hip/hip_runtime.h>

#define B_   4
#define S_   256
#define E_   256
#define H_   8
#define LD_  128
#define N_   65536
#define NC_  2

typedef __attribute__((ext_vector_type(8))) short s8v;   // 8 bf16
typedef __attribute__((ext_vector_type(4))) float f32x4;

__device__ __forceinline__ short f2bf(float f) {
  union { float f; unsigned u; } v; v.f = f;
  unsigned r = (v.u + 0x7FFFu + ((v.u >> 16) & 1u)) >> 16;   // RNE
  return (short)r;
}
__device__ __forceinline__ float bf2f(short s) {
  union { float f; unsigned u; } v; v.u = ((unsigned)(unsigned short)s) << 16;
  return v.f;
}
__device__ __forceinline__ s8v pack8(float4 a, float4 b) {
  s8v r;
  r[0] = f2bf(a.x); r[1] = f2bf(a.y); r[2] = f2bf(a.z); r[3] = f2bf(a.w);
  r[4] = f2bf(b.x); r[5] = f2bf(b.y); r[6] = f2bf(b.z); r[7] = f2bf(b.w);
  return r;
}

// ---------------------------------------------------------------------------
// prep_k: one kernel, three block-roles (all independent):
//   bid <  768          : weight convert / split + bn fold
//   768 <= bid <= 1024  : ids fill (per-block local prefix reduce)
//   bid >= 1025         : pos-MLP + gl^T add -> Xhi/Xlo
// ---------------------------------------------------------------------------
__global__ __launch_bounds__(256) void prep_k(
    const int* __restrict__ npc, int* __restrict__ ids,
    const float* __restrict__ ipw, const float* __restrict__ opw,
    const float* __restrict__ w2, const float* __restrict__ w3,
    const float* __restrict__ b2, const float* __restrict__ g2,
    const float* __restrict__ be2, const float* __restrict__ mu2,
    const float* __restrict__ va2,
    const float* __restrict__ b3, const float* __restrict__ g3,
    const float* __restrict__ be3, const float* __restrict__ mu3,
    const float* __restrict__ va3,
    short* __restrict__ iph, short* __restrict__ ipl,
    short* __restrict__ oph, short* __restrict__ opl,
    short* __restrict__ w2bf, short* __restrict__ w3bf,
    float* __restrict__ sc2, float* __restrict__ sh2,
    float* __restrict__ sc3, float* __restrict__ sh3,
    const float* __restrict__ gl, const float* __restrict__ cen,
    const float* __restrict__ fc1w, const float* __restrict__ fc1b,
    const float* __restrict__ fc2w, const float* __restrict__ fc2b,
    short* __restrict__ Xhi, short* __restrict__ Xlo) {
  __shared__ int red[256];
  __shared__ float hsh[16];
  int bid = blockIdx.x, t = threadIdx.x;
  if (bid < 768) {
    int i = bid * 256 + t;
    if (i < 196608) {
      float v = ipw[i]; short h = f2bf(v);
      iph[i] = h; ipl[i] = f2bf(v - bf2f(h));
    }
    if (i < 65536) {
      float v = opw[i]; short h = f2bf(v);
      oph[i] = h; opl[i] = f2bf(v - bf2f(h));
    }
    if (i < 49152) w2bf[i] = f2bf(w2[i]);
    if (i < 8192)  w3bf[i] = f2bf(w3[i]);
    if (i < 128) {
      float sc = g2[i] * rsqrtf(va2[i] + 1e-5f);
      sc2[i] = sc; sh2[i] = (b2[i] - mu2[i]) * sc + be2[i];
    }
    if (i < 64) {
      float sc = g3[i] * rsqrtf(va3[i] + 1e-5f);
      sc3[i] = sc; sh3[i] = (b3[i] - mu3[i]) * sc + be3[i];
    }
  } else if (bid <= 1024) {
    int s = bid - 768;   // 0..256
    int val = (s == 256) ? npc[t] : ((t < s) ? npc[t] : 0);
    red[t] = val;
    __syncthreads();
    for (int off = 128; off > 0; off >>= 1) {
      if (t < off) red[t] += red[t + off];
      __syncthreads();
    }
    int st = red[0];
    if (s < 256) {
      int en = st + npc[s]; if (en > N_) en = N_;
      for (int n = st + t; n < en; n += 256) ids[n] = s;
    } else {
      for (int n = st + t; n < N_; n += 256) ids[n] = 255;
    }
  } else {
    int bs = bid - 1025;   // 0..1023
    int b = bs >> 8, s = bs & 255;
    if (t < 16) {
      float c0 = cen[bs * 2 + 0], c1 = cen[bs * 2 + 1];
      float v = c0 * fc1w[2 * t] + c1 * fc1w[2 * t + 1] + fc1b[t];
      hsh[t] = (v >= 0.f) ? v : 0.01f * v;
    }
    __syncthreads();
    float p = fc2b[t];
#pragma unroll
    for (int j = 0; j < 16; j++) p += hsh[j] * fc2w[t * 16 + j];
    float v = gl[((size_t)s * B_ + b) * E_ + t] + p;
    short h = f2bf(v);
    Xhi[(size_t)bs * E_ + t] = h;
    Xlo[(size_t)bs * E_ + t] = f2bf(v - bf2f(h));
  }
}

// ---------------------------------------------------------------------------
// bf16x3 MFMA GEMM (qkv): C = (Ah+Al)(Wh+Wl)^T + bias
// ---------------------------------------------------------------------------
__global__ __launch_bounds__(256) void gemm_x3_k(
    const short* __restrict__ Ah, const short* __restrict__ Al,
    const short* __restrict__ Wh, const short* __restrict__ Wl,
    const float* __restrict__ bias, float* __restrict__ Cf,
    int M, int N, int K) {
  __shared__ __align__(16) short gs[18432];
  const int AH = 0, AL = 4608, WH = 9216, WL = 13824;
  int t = threadIdx.x;
  int row0 = blockIdx.x * 64, col0 = blockIdx.y * 64;
  int w = t >> 6, l = t & 63, quad = l >> 4, lr = l & 15;
  int m0 = w * 16;
  int ar = t >> 2, aq = (t & 3) * 16;
  f32x4 acc[4];
#pragma unroll
  for (int i = 0; i < 4; i++) acc[i] = (f32x4)(0.f);

  for (int kc = 0; kc < K; kc += 64) {
    __syncthreads();
    {
      size_t ra = (size_t)(row0 + ar) * K + kc + aq;
      size_t rw = (size_t)(col0 + ar) * K + kc + aq;
      *(s8v*)&gs[AH + ar * 72 + aq]     = *(const s8v*)&Ah[ra];
      *(s8v*)&gs[AH + ar * 72 + aq + 8] = *(const s8v*)&Ah[ra + 8];
      *(s8v*)&gs[AL + ar * 72 + aq]     = *(const s8v*)&Al[ra];
      *(s8v*)&gs[AL + ar * 72 + aq + 8] = *(const s8v*)&Al[ra + 8];
      *(s8v*)&gs[WH + ar * 72 + aq]     = *(const s8v*)&Wh[rw];
      *(s8v*)&gs[WH + ar * 72 + aq + 8] = *(const s8v*)&Wh[rw + 8];
      *(s8v*)&gs[WL + ar * 72 + aq]     = *(const s8v*)&Wl[rw];
      *(s8v*)&gs[WL + ar * 72 + aq + 8] = *(const s8v*)&Wl[rw + 8];
    }
    __syncthreads();
#pragma unroll
    for (int ks = 0; ks < 2; ks++) {
      int ko = ks * 32 + quad * 8;
      s8v ah = *(const s8v*)&gs[AH + (m0 + lr) * 72 + ko];
      s8v al = *(const s8v*)&gs[AL + (m0 + lr) * 72 + ko];
#pragma unroll
      for (int ct = 0; ct < 4; ct++) {
        s8v bh = *(const s8v*)&gs[WH + (ct * 16 + lr) * 72 + ko];
        s8v bl = *(const s8v*)&gs[WL + (ct * 16 + lr) * 72 + ko];
        acc[ct] = __builtin_amdgcn_mfma_f32_16x16x32_bf16(ah, bh, acc[ct], 0, 0, 0);
        acc[ct] = __builtin_amdgcn_mfma_f32_16x16x32_bf16(al, bh, acc[ct], 0, 0, 0);
        acc[ct] = __builtin_amdgcn_mfma_f32_16x16x32_bf16(ah, bl, acc[ct], 0, 0, 0);
      }
    }
  }
#pragma unroll
  for (int ct = 0; ct < 4; ct++) {
    int c = col0 + ct * 16 + lr;
    float bb = bias[c];
#pragma unroll
    for (int rg = 0; rg < 4; rg++) {
      int r = row0 + m0 + quad * 4 + rg;
      Cf[(size_t)r * N + c] = acc[ct][rg] + bb;
    }
  }
}

// ---------------------------------------------------------------------------
// attention (unchanged from round 3)
// ---------------------------------------------------------------------------
__global__ __launch_bounds__(256) void attn_k(const float* __restrict__ qkv,
                                              short* __restrict__ Chi,
                                              short* __restrict__ Clo) {
  int bid = blockIdx.x;
  int qt = bid & 7, h = (bid >> 3) & 7, b = bid >> 6;
  __shared__ __align__(16) float smem[16384];
  float* Kx = smem;
  float* Vx = smem + 8192;
  int t = threadIdx.x;
#pragma unroll
  for (int i = 0; i < 8; i++) {
    int row = i * 32 + (t >> 3);
    int d4 = (t & 7) * 4;
    const float* base = qkv + (size_t)(b * S_ + row) * 768 + h * 32 + d4;
    *(float4*)&Kx[row * 32 + d4] = *(const float4*)(base + 256);
    *(float4*)&Vx[row * 32 + d4] = *(const float4*)(base + 512);
  }
  int r = t & 31, g = t >> 5;
  float q[32];
  {
    const float* qb = qkv + (size_t)(b * S_ + qt * 32 + r) * 768 + h * 32;
#pragma unroll
    for (int d4 = 0; d4 < 32; d4 += 4) {
      float4 v = *(const float4*)(qb + d4);
      q[d4] = v.x; q[d4 + 1] = v.y; q[d4 + 2] = v.z; q[d4 + 3] = v.w;
    }
  }
  __syncthreads();
  const float scale = 0.17677669529663687f;
  int kk0 = g * 32;
  float sc[32];
  float m = -1e30f;
#pragma unroll
  for (int kk = 0; kk < 32; kk++) {
    const float* kr = &Kx[(kk0 + kk) * 32];
    float4 a = (float4){0.f, 0.f, 0.f, 0.f};
#pragma unroll
    for (int d4 = 0; d4 < 32; d4 += 4) {
      float4 kv = *(const float4*)(kr + d4);
      a.x += q[d4] * kv.x; a.y += q[d4 + 1] * kv.y;
      a.z += q[d4 + 2] * kv.z; a.w += q[d4 + 3] * kv.w;
    }
    float s = ((a.x + a.y) + (a.z + a.w)) * scale;
    sc[kk] = s;
    m = fmaxf(m, s);
  }
  float lsum = 0.f;
  float ctx[32];
#pragma unroll
  for (int d = 0; d < 32; d++) ctx[d] = 0.f;
#pragma unroll
  for (int kk = 0; kk < 32; kk++) {
    const float* vr = &Vx[(kk0 + kk) * 32];
    float p = __expf(sc[kk] - m);
    lsum += p;
#pragma unroll
    for (int d4 = 0; d4 < 32; d4 += 4) {
      float4 vv = *(const float4*)(vr + d4);
      ctx[d4] += p * vv.x; ctx[d4 + 1] += p * vv.y;
      ctx[d4 + 2] += p * vv.z; ctx[d4 + 3] += p * vv.w;
    }
  }
  __syncthreads();
  float* ctxbuf = smem;
  float* mbuf = smem + 8192;
  float* lbuf = smem + 8448;
  mbuf[g * 32 + r] = m;
  lbuf[g * 32 + r] = lsum;
#pragma unroll
  for (int d = 0; d < 32; d++)
    ctxbuf[(g * 32 + r) * 32 + ((d + r) & 31)] = ctx[d];
  __syncthreads();
  int r2 = t & 31, dq = t >> 5;
  float M = -1e30f;
#pragma unroll
  for (int gg = 0; gg < 8; gg++) M = fmaxf(M, mbuf[gg * 32 + r2]);
  float wg[8]; float L = 0.f;
#pragma unroll
  for (int gg = 0; gg < 8; gg++) {
    wg[gg] = __expf(mbuf[gg * 32 + r2] - M);
    L += lbuf[gg * 32 + r2] * wg[gg];
  }
  float invL = 1.f / L;
  size_t base = (size_t)(b * S_ + qt * 32 + r2) * E_ + h * 32;
#pragma unroll
  for (int dd = 0; dd < 4; dd++) {
    int d = dq * 4 + dd;
    float o = 0.f;
#pragma unroll
    for (int gg = 0; gg < 8; gg++)
      o += ctxbuf[(gg * 32 + r2) * 32 + ((d + r2) & 31)] * wg[gg];
    o *= invL;
    short hi = f2bf(o);
    Chi[base + d] = hi;
    Clo[base + d] = f2bf(o - bf2f(hi));
  }
}

// ---------------------------------------------------------------------------
// opg_k: fused out_proj (bf16x3) + G = attn_out @ W2b^T (bf16).
// 16 blocks x 64 rows. Phase 1: attn_out 64x256 tile -> bf16 in LDS.
// Phase 2: G 64x128 via MFMA from LDS. attn_out never hits HBM.
// LDS: phase1 stage 92160 B; phase2 Ct(33792)+W2b(67584) = 101376 B.
// ---------------------------------------------------------------------------
__global__ __launch_bounds__(256) void opg_k(
    const short* __restrict__ Chi, const short* __restrict__ Clo,
    const short* __restrict__ oph, const short* __restrict__ opl,
    const float* __restrict__ opb, const short* __restrict__ w2bf,
    float* __restrict__ G) {
  __shared__ __align__(16) short gsm[50688];   // 101376 B
  const int AH = 0, AL = 4608, WH = 9216, WL = 27648;   // phase 1 (shorts)
  const int CT = 0, W2B = 16896;                         // phase 2 (shorts)
  int t = threadIdx.x;
  int row0 = blockIdx.x * 64;
  int w = t >> 6, l = t & 63, quad = l >> 4, lr = l & 15;

  f32x4 acc[16];
#pragma unroll
  for (int i = 0; i < 16; i++) acc[i] = (f32x4)(0.f);

  for (int kc = 0; kc < 256; kc += 64) {
    __syncthreads();
    {  // stage W: 256 rows x 64 k (hi+lo)
#pragma unroll
      for (int j = 0; j < 8; j++) {
        *(s8v*)&gsm[WH + t * 72 + j * 8] = *(const s8v*)&oph[(size_t)t * 256 + kc + j * 8];
        *(s8v*)&gsm[WL + t * 72 + j * 8] = *(const s8v*)&opl[(size_t)t * 256 + kc + j * 8];
      }
      // stage A: 64 rows x 64 k (hi+lo)
      if (t < 128) {
        int row = t >> 1, half = (t & 1) * 32;
        size_t ra = (size_t)(row0 + row) * 256 + kc + half;
#pragma unroll
        for (int j = 0; j < 4; j++) {
          *(s8v*)&gsm[AH + row * 72 + half + j * 8] = *(const s8v*)&Chi[ra + j * 8];
          *(s8v*)&gsm[AL + row * 72 + half + j * 8] = *(const s8v*)&Clo[ra + j * 8];
        }
      }
    }
    __syncthreads();
#pragma unroll
    for (int ks = 0; ks < 2; ks++) {
      int ko = ks * 32 + quad * 8;
      s8v ah = *(const s8v*)&gsm[AH + (w * 16 + lr) * 72 + ko];
      s8v al = *(const s8v*)&gsm[AL + (w * 16 + lr) * 72 + ko];
#pragma unroll
      for (int ct = 0; ct < 16; ct++) {
        s8v bh = *(const s8v*)&gsm[WH + (ct * 16 + lr) * 72 + ko];
        s8v bl = *(const s8v*)&gsm[WL + (ct * 16 + lr) * 72 + ko];
        acc[ct] = __builtin_amdgcn_mfma_f32_16x16x32_bf16(ah, bh, acc[ct], 0, 0, 0);
        acc[ct] = __builtin_amdgcn_mfma_f32_16x16x32_bf16(al, bh, acc[ct], 0, 0, 0);
        acc[ct] = __builtin_amdgcn_mfma_f32_16x16x32_bf16(ah, bl, acc[ct], 0, 0, 0);
      }
    }
  }
  __syncthreads();
  // epilogue phase 1: attn_out tile -> Ct (bf16); stage W2b (w2 cols 128..383)
#pragma unroll
  for (int ct = 0; ct < 16; ct++) {
    int c = ct * 16 + lr;
    float bb = opb[c];
#pragma unroll
    for (int rg = 0; rg < 4; rg++) {
      int r = w * 16 + quad * 4 + rg;
      gsm[CT + r * 264 + c] = f2bf(acc[ct][rg] + bb);
    }
  }
  {
    int ch = t >> 1, koff = (t & 1) * 128;
#pragma unroll
    for (int j = 0; j < 16; j++)
      *(s8v*)&gsm[W2B + ch * 264 + koff + j * 8] =
          *(const s8v*)&w2bf[(size_t)ch * 384 + 128 + koff + j * 8];
  }
  __syncthreads();
  // phase 2: G[64][128] = Ct @ W2b^T
  f32x4 acc2[8];
#pragma unroll
  for (int i = 0; i < 8; i++) acc2[i] = (f32x4)(0.f);
#pragma unroll
  for (int ks = 0; ks < 8; ks++) {
    int ko = ks * 32 + quad * 8;
    s8v a = *(const s8v*)&gsm[CT + (w * 16 + lr) * 264 + ko];
#pragma unroll
    for (int ct = 0; ct < 8; ct++) {
      s8v b = *(const s8v*)&gsm[W2B + (ct * 16 + lr) * 264 + ko];
      acc2[ct] = __builtin_amdgcn_mfma_f32_16x16x32_bf16(a, b, acc2[ct], 0, 0, 0);
    }
  }
#pragma unroll
  for (int ct = 0; ct < 8; ct++) {
    int c = ct * 16 + lr;
#pragma unroll
    for (int rg = 0; rg < 4; rg++) {
      int r = row0 + w * 16 + quad * 4 + rg;
      G[(size_t)r * 128 + c] = acc2[ct][rg];
    }
  }
}

// ---------------------------------------------------------------------------
// conv_fused: conv2 (K=128, lo only) + G-gather + bn2/relu -> conv3 -> conv4.
// Block = 128 pts, 4 waves; W2a staged once; LDS 53248 B + ids -> 3 blocks/CU.
// ---------------------------------------------------------------------------
#define CF_SW2 0        // [128][136] shorts (W2a full K=128)
#define CF_SA  17408    // [128][72]
#define CF_H2  0        // [128][136]  (over SW2)
#define CF_SW3 17408    // [64][136]   (over SA)
#define CF_H3  0        // [128][72]   (over H2)

__global__ __launch_bounds__(256, 3) void conv_fused_k(
    const float* __restrict__ lo, const float* __restrict__ G,
    const int* __restrict__ ids,
    const short* __restrict__ w2bf, const short* __restrict__ w3bf,
    const float* __restrict__ sc2, const float* __restrict__ sh2,
    const float* __restrict__ sc3, const float* __restrict__ sh3,
    const float* __restrict__ w4, const float* __restrict__ b4,
    float* __restrict__ out) {
  __shared__ __align__(16) short smem[26624];  // 53248 B
  __shared__ int lds_ids[128];
  int t = threadIdx.x;
  int bid = blockIdx.x;
  int b = bid >> 9;
  int n0 = (bid & 511) << 7;
  int w = t >> 6, l = t & 63;
  int quad = l >> 4, lr = l & 15;
  int mh = w & 1, chh = w >> 1;
  int ar = t >> 1, akh = (t & 1) * 32;
  const float* lob = &lo[((size_t)b * N_ + n0 + ar) * LD_ + akh];

  // prologue: stage W2a (full), ids, A chunk 0
  {
    int ch = t >> 1, koff = (t & 1) * 64;
#pragma unroll
    for (int j = 0; j < 8; j++)
      *(s8v*)&smem[CF_SW2 + ch * 136 + koff + j * 8] =
          *(const s8v*)&w2bf[(size_t)ch * 384 + koff + j * 8];
  }
  if (t < 128) lds_ids[t] = ids[n0 + t];
  float4 pf[8];
#pragma unroll
  for (int j = 0; j < 8; j++) pf[j] = *(const float4*)(lob + j * 4);
#pragma unroll
  for (int j = 0; j < 4; j++)
    *(s8v*)&smem[CF_SA + ar * 72 + akh + j * 8] = pack8(pf[2 * j], pf[2 * j + 1]);
  __syncthreads();

  // prefetch A chunk 1 while MFMA chunk 0
#pragma unroll
  for (int j = 0; j < 8; j++) pf[j] = *(const float4*)(lob + 64 + j * 4);

  f32x4 acc2[4][4];
#pragma unroll
  for (int i = 0; i < 4; i++)
#pragma unroll
    for (int j = 0; j < 4; j++) acc2[i][j] = (f32x4)(0.f);

#pragma unroll
  for (int ks = 0; ks < 2; ks++) {
    int ko = ks * 32 + quad * 8;
    s8v af[4], bf[4];
#pragma unroll
    for (int mt = 0; mt < 4; mt++)
      af[mt] = *(const s8v*)&smem[CF_SA + (64 * mh + 16 * mt + lr) * 72 + ko];
#pragma unroll
    for (int ct = 0; ct < 4; ct++)
      bf[ct] = *(const s8v*)&smem[CF_SW2 + (64 * chh + 16 * ct + lr) * 136 + ko];
#pragma unroll
    for (int mt = 0; mt < 4; mt++)
#pragma unroll
      for (int ct = 0; ct < 4; ct++)
        acc2[mt][ct] = __builtin_amdgcn_mfma_f32_16x16x32_bf16(af[mt], bf[ct], acc2[mt][ct], 0, 0, 0);
  }
  __syncthreads();
#pragma unroll
  for (int j = 0; j < 4; j++)
    *(s8v*)&smem[CF_SA + ar * 72 + akh + j * 8] = pack8(pf[2 * j], pf[2 * j + 1]);
  __syncthreads();
#pragma unroll
  for (int ks = 0; ks < 2; ks++) {
    int koA = ks * 32 + quad * 8;
    int koW = 64 + koA;
    s8v af[4], bf[4];
#pragma unroll
    for (int mt = 0; mt < 4; mt++)
      af[mt] = *(const s8v*)&smem[CF_SA + (64 * mh + 16 * mt + lr) * 72 + koA];
#pragma unroll
    for (int ct = 0; ct < 4; ct++)
      bf[ct] = *(const s8v*)&smem[CF_SW2 + (64 * chh + 16 * ct + lr) * 136 + koW];
#pragma unroll
    for (int mt = 0; mt < 4; mt++)
#pragma unroll
      for (int ct = 0; ct < 4; ct++)
        acc2[mt][ct] = __builtin_amdgcn_mfma_f32_16x16x32_bf16(af[mt], bf[ct], acc2[mt][ct], 0, 0, 0);
  }
  __syncthreads();  // SW2/SA reads done everywhere

  // epilogue: gather G, bn2+relu -> H2; stage w3 -> SW3
#pragma unroll
  for (int ct = 0; ct < 4; ct++) {
    int c = 64 * chh + 16 * ct + lr;
    float sc = sc2[c], sh = sh2[c];
    float gv[4][4];
#pragma unroll
    for (int mt = 0; mt < 4; mt++)
#pragma unroll
      for (int rg = 0; rg < 4; rg++) {
        int p = 64 * mh + 16 * mt + 4 * quad + rg;
        gv[mt][rg] = G[((size_t)b * 256 + lds_ids[p]) * 128 + c];
      }
#pragma unroll
    for (int mt = 0; mt < 4; mt++)
#pragma unroll
      for (int rg = 0; rg < 4; rg++) {
        int p = 64 * mh + 16 * mt + 4 * quad + rg;
        float z = (acc2[mt][ct][rg] + gv[mt][rg]) * sc + sh;
        smem[CF_H2 + p * 136 + c] = f2bf(fmaxf(z, 0.f));
      }
  }
  {
    int ch = t >> 2, kq = (t & 3) * 32;
#pragma unroll
    for (int j = 0; j < 4; j++)
      *(s8v*)&smem[CF_SW3 + ch * 136 + kq + j * 8] =
          *(const s8v*)&w3bf[ch * 128 + kq + j * 8];
  }
  __syncthreads();

  // conv3: 128 pts x 64 ch, K=128; wave = 32 pts x 64 ch
  f32x4 acc3[2][4];
#pragma unroll
  for (int i = 0; i < 2; i++)
#pragma unroll
    for (int j = 0; j < 4; j++) acc3[i][j] = (f32x4)(0.f);
#pragma unroll
  for (int ks = 0; ks < 4; ks++) {
    int ko = ks * 32 + quad * 8;
    s8v af[2], bf[4];
#pragma unroll
    for (int mt = 0; mt < 2; mt++)
      af[mt] = *(const s8v*)&smem[CF_H2 + (32 * w + 16 * mt + lr) * 136 + ko];
#pragma unroll
    for (int ct = 0; ct < 4; ct++)
      bf[ct] = *(const s8v*)&smem[CF_SW3 + (16 * ct + lr) * 136 + ko];
#pragma unroll
    for (int mt = 0; mt < 2; mt++)
#pragma unroll
      for (int ct = 0; ct < 4; ct++)
        acc3[mt][ct] = __builtin_amdgcn_mfma_f32_16x16x32_bf16(af[mt], bf[ct], acc3[mt][ct], 0, 0, 0);
  }
  __syncthreads();  // H2 reads done before overlaying with H3

  // bn3 + relu -> H3
#pragma unroll
  for (int ct = 0; ct < 4; ct++) {
    int c = 16 * ct + lr;
    float sc = sc3[c], sh = sh3[c];
#pragma unroll
    for (int mt = 0; mt < 2; mt++)
#pragma unroll
      for (int rg = 0; rg < 4; rg++) {
        int p = 32 * w + 16 * mt + 4 * quad + rg;
        float z = acc3[mt][ct][rg] * sc + sh;
        smem[CF_H3 + p * 72 + c] = f2bf(fmaxf(z, 0.f));
      }
  }
  __syncthreads();

  // conv4 (fp32)
  {
    int c = t >> 7, p = t & 127;
    float s = b4[c];
#pragma unroll
    for (int j = 0; j < 8; j++) {
      s8v hv = *(const s8v*)&smem[CF_H3 + p * 72 + j * 8];
#pragma unroll
      for (int e = 0; e < 8; e++)
        s += bf2f(hv[e]) * w4[c * 64 + j * 8 + e];
    }
    out[((size_t)b * NC_ + c) * N_ + n0 + p] = s;
  }
}

// ---------------------------------------------------------------------------
extern "C" void kernel_launch(void* const* d_in, const int* in_sizes, int n_in,
                              void* d_out, int out_size, void* d_ws, size_t ws_size,
                              hipStream_t stream) {
  const float* gl   = (const float*)d_in[0];
  const float* lo   = (const float*)d_in[1];
  const float* cen  = (const float*)d_in[2];
  const int*   npc  = (const int*)d_in[3];
  const float* fc1w = (const float*)d_in[4];
  const float* fc1b = (const float*)d_in[5];
  const float* fc2w = (const float*)d_in[6];
  const float* fc2b = (const float*)d_in[7];
  const float* ipw  = (const float*)d_in[8];
  const float* ipb  = (const float*)d_in[9];
  const float* opw  = (const float*)d_in[10];
  const float* opb  = (const float*)d_in[11];
  const float* w2   = (const float*)d_in[12];
  const float* b2   = (const float*)d_in[13];
  const float* g2   = (const float*)d_in[14];
  const float* be2  = (const float*)d_in[15];
  const float* mu2  = (const float*)d_in[16];
  const float* va2  = (const float*)d_in[17];
  const float* w3   = (const float*)d_in[18];
  const float* b3   = (const float*)d_in[19];
  const float* g3   = (const float*)d_in[20];
  const float* be3  = (const float*)d_in[21];
  const float* mu3  = (const float*)d_in[22];
  const float* va3  = (const float*)d_in[23];
  const float* w4   = (const float*)d_in[24];
  const float* b4   = (const float*)d_in[25];

  char* ws = (char*)d_ws;
  float* qkv  = (float*)(ws);                  // 3,145,728
  short* Xhi  = (short*)(ws + 3145728);        // 524,288
  short* Xlo  = (short*)(ws + 3670016);
  short* Chi  = (short*)(ws + 4194304);
  short* Clo  = (short*)(ws + 4718592);
  float* G    = (float*)(ws + 5242880);        // 524,288 (B,256,128) fp32
  short* iph  = (short*)(ws + 5767168);        // 393,216
  short* ipl  = (short*)(ws + 6160384);
  short* oph  = (short*)(ws + 6553600);        // 131,072
  short* opl  = (short*)(ws + 6684672);
  short* w2bf = (short*)(ws + 6815744);        // 98,304
  short* w3bf = (short*)(ws + 6914048);        // 16,384
  int*   ids  = (int*)  (ws + 6930432);        // 262,144
  float* sc2  = (float*)(ws + 7192576);
  float* sh2  = (float*)(ws + 7193088);
  float* sc3  = (float*)(ws + 7193600);
  float* sh3  = (float*)(ws + 7193856);
  float* out  = (float*)d_out;

  prep_k<<<2049, 256, 0, stream>>>(npc, ids, ipw, opw, w2, w3,
                                   b2, g2, be2, mu2, va2,
                                   b3, g3, be3, mu3, va3,
                                   iph, ipl, oph, opl, w2bf, w3bf,
                                   sc2, sh2, sc3, sh3,
                                   gl, cen, fc1w, fc1b, fc2w, fc2b, Xhi, Xlo);
  gemm_x3_k<<<dim3(16, 12), 256, 0, stream>>>(Xhi, Xlo, iph, ipl, ipb,
                                              qkv, B_ * S_, 768, E_);
  attn_k<<<B_ * H_ * 8, 256, 0, stream>>>(qkv, Chi, Clo);
  opg_k<<<16, 256, 0, stream>>>(Chi, Clo, oph, opl, opb, w2bf, G);
  conv_fused_k<<<B_ * (N_ / 128), 256, 0, stream>>>(
      lo, G, ids, w2bf, w3bf, sc2, sh2, sc3, sh3, w4, b4, out);
}